// Round 1
// baseline (1428.291 us; speedup 1.0000x reference)
//
#include <hip/hip_runtime.h>
#include <math.h>

#define B_SZ 2
#define L_SEQ 2048
#define H_SZ 1024
#define NH 16
#define HD 64

// ---------------------------------------------------------------------------
// RoPE tables: combined spatial(2D over 16x16 grid indexed by s=l%256) +
// temporal(1D indexed by ti=l/256) rotation angles. Two sequential 2D
// rotations on the same (even,odd) pair = one rotation by the angle sum.
// cos/sin stored per (l, j) for l in [0,2048), j in [0,32).
// ---------------------------------------------------------------------------
__global__ void rope_table_k(float* __restrict__ cosb, float* __restrict__ sinb) {
  int idx = blockIdx.x * blockDim.x + threadIdx.x;
  if (idx >= L_SEQ * 32) return;
  int l = idx >> 5, j = idx & 31;
  int ti = l >> 8;        // temporal index (t=8 major blocks of 256)
  int s = l & 255;        // spatial index within 16x16 grid
  float ang_s;
  if (j < 16) ang_s = (float)(s & 15) * powf(10000.f, -(float)j / 16.f);       // x-axis
  else        ang_s = (float)(s >> 4) * powf(10000.f, -(float)(j - 16) / 16.f); // y-axis
  float ang_t = (float)ti * powf(10000.f, -(float)j / 32.f);
  float a = ang_s + ang_t;
  cosb[idx] = cosf(a);
  sinb[idx] = sinf(a);
}

// ---------------------------------------------------------------------------
// GEMM1: qkv[4096][3072] = x[4096][1024] @ w_qkv[3072][1024]^T + b_qkv
// fp32 tiled: 64x64 tile, BK=16, 256 threads, 4x4 per thread.
// ---------------------------------------------------------------------------
__global__ __launch_bounds__(256) void gemm_qkv_k(
    const float* __restrict__ A, const float* __restrict__ W,
    const float* __restrict__ bias, float* __restrict__ C) {
  const int K = 1024, N = 3072;
  __shared__ float As[64][17];
  __shared__ float Ws[64][17];
  int tid = threadIdx.x;
  int tr = tid >> 4, tc = tid & 15;
  int m0 = blockIdx.y * 64, n0 = blockIdx.x * 64;
  int lrow = tid >> 2, lkq = (tid & 3) * 4;
  float acc[4][4] = {};
  for (int k0 = 0; k0 < K; k0 += 16) {
    float4 av = *(const float4*)&A[(size_t)(m0 + lrow) * K + k0 + lkq];
    float4 wv = *(const float4*)&W[(size_t)(n0 + lrow) * K + k0 + lkq];
    As[lrow][lkq] = av.x; As[lrow][lkq + 1] = av.y; As[lrow][lkq + 2] = av.z; As[lrow][lkq + 3] = av.w;
    Ws[lrow][lkq] = wv.x; Ws[lrow][lkq + 1] = wv.y; Ws[lrow][lkq + 2] = wv.z; Ws[lrow][lkq + 3] = wv.w;
    __syncthreads();
#pragma unroll
    for (int kk = 0; kk < 16; ++kk) {
      float a[4], b[4];
#pragma unroll
      for (int i = 0; i < 4; ++i) a[i] = As[tr * 4 + i][kk];
#pragma unroll
      for (int j = 0; j < 4; ++j) b[j] = Ws[tc * 4 + j][kk];
#pragma unroll
      for (int i = 0; i < 4; ++i)
#pragma unroll
        for (int j = 0; j < 4; ++j)
          acc[i][j] = fmaf(a[i], b[j], acc[i][j]);
    }
    __syncthreads();
  }
#pragma unroll
  for (int i = 0; i < 4; ++i)
#pragma unroll
    for (int j = 0; j < 4; ++j)
      C[(size_t)(m0 + tr * 4 + i) * N + n0 + tc * 4 + j] = acc[i][j] + bias[n0 + tc * 4 + j];
}

// ---------------------------------------------------------------------------
// RoPE + scatter: qkv[(b,l), n*192 + {q:0..63, k:64..127, v:128..191}]
//   -> Q/K/V in (B, NH, L, HD) layout; RoPE applied to q,k pairs.
// One thread per (b, l, n, pair j).
// ---------------------------------------------------------------------------
__global__ void rope_scatter_k(const float* __restrict__ qkv,
                               const float* __restrict__ cosb,
                               const float* __restrict__ sinb,
                               float* __restrict__ Q, float* __restrict__ Kb,
                               float* __restrict__ V) {
  int tid = blockIdx.x * blockDim.x + threadIdx.x;  // B*L*NH*32 = 2,097,152
  int j = tid & 31;
  int n = (tid >> 5) & (NH - 1);
  int l = (tid >> 9) & (L_SEQ - 1);
  int b = tid >> 20;
  size_t base = ((size_t)(b * L_SEQ + l)) * 3072 + n * 192;
  float cr = cosb[l * 32 + j], sr = sinb[l * 32 + j];
  size_t ob = ((size_t)((b * NH + n) * L_SEQ + l)) * HD;
  float qr = qkv[base + 2 * j], qi = qkv[base + 2 * j + 1];
  Q[ob + 2 * j] = qr * cr - qi * sr;
  Q[ob + 2 * j + 1] = qr * sr + qi * cr;
  float kr = qkv[base + 64 + 2 * j], ki = qkv[base + 64 + 2 * j + 1];
  Kb[ob + 2 * j] = kr * cr - ki * sr;
  Kb[ob + 2 * j + 1] = kr * sr + ki * cr;
  V[ob + 2 * j] = qkv[base + 128 + 2 * j];
  V[ob + 2 * j + 1] = qkv[base + 128 + 2 * j + 1];
}

// ---------------------------------------------------------------------------
// Flash-style causal attention, fp32. One block = 64 query rows of one
// (b, head). Online softmax (running m, l), causal tile skipping.
// ---------------------------------------------------------------------------
__global__ __launch_bounds__(256) void attn_k(
    const float* __restrict__ Qg, const float* __restrict__ Kg,
    const float* __restrict__ Vg, float* __restrict__ Og) {
  __shared__ float Qs[64][65], Ks[64][65], Vs[64][65], Ss[64][65];
  __shared__ float m_s[64], l_s[64], coef_s[64], red[64][4];
  int bx = blockIdx.x;
  int qt = bx & 31;
  int n = (bx >> 5) & 15;
  int b = bx >> 9;
  int q0 = qt * 64;
  size_t headoff = (size_t)(b * NH + n) * L_SEQ * HD;
  int tid = threadIdx.x, tr = tid >> 4, tc = tid & 15;

  // load Q tile (64x64), coalesced float4
#pragma unroll
  for (int v = 0; v < 4; ++v) {
    int f = tid + v * 256;
    int row = f >> 4, c4 = (f & 15) * 4;
    float4 qv = *(const float4*)&Qg[headoff + (size_t)(q0 + row) * HD + c4];
    Qs[row][c4] = qv.x; Qs[row][c4 + 1] = qv.y; Qs[row][c4 + 2] = qv.z; Qs[row][c4 + 3] = qv.w;
  }
  if (tid < 64) { m_s[tid] = -1e30f; l_s[tid] = 0.f; }
  float acc[4][4] = {};
  int ktmax = (q0 + 63) >> 6;  // causal: only tiles with k0 <= q0+63
  for (int kt = 0; kt <= ktmax; ++kt) {
    int k0 = kt * 64;
#pragma unroll
    for (int v = 0; v < 4; ++v) {
      int f = tid + v * 256;
      int row = f >> 4, c4 = (f & 15) * 4;
      float4 kv = *(const float4*)&Kg[headoff + (size_t)(k0 + row) * HD + c4];
      Ks[row][c4] = kv.x; Ks[row][c4 + 1] = kv.y; Ks[row][c4 + 2] = kv.z; Ks[row][c4 + 3] = kv.w;
      float4 vv = *(const float4*)&Vg[headoff + (size_t)(k0 + row) * HD + c4];
      Vs[row][c4] = vv.x; Vs[row][c4 + 1] = vv.y; Vs[row][c4 + 2] = vv.z; Vs[row][c4 + 3] = vv.w;
    }
    __syncthreads();

    // S = Q K^T (4x4 per thread)
    float sacc[4][4] = {};
    for (int kk = 0; kk < 64; ++kk) {
      float a[4], bb[4];
#pragma unroll
      for (int i = 0; i < 4; ++i) a[i] = Qs[tr * 4 + i][kk];
#pragma unroll
      for (int j = 0; j < 4; ++j) bb[j] = Ks[tc * 4 + j][kk];
#pragma unroll
      for (int i = 0; i < 4; ++i)
#pragma unroll
        for (int j = 0; j < 4; ++j)
          sacc[i][j] = fmaf(a[i], bb[j], sacc[i][j]);
    }
    // scale + causal mask, store to Ss
#pragma unroll
    for (int i = 0; i < 4; ++i)
#pragma unroll
      for (int j = 0; j < 4; ++j) {
        int qi = q0 + tr * 4 + i, ki = k0 + tc * 4 + j;
        Ss[tr * 4 + i][tc * 4 + j] = (ki <= qi) ? sacc[i][j] * 0.125f : -1e30f;
      }
    __syncthreads();

    // row max (4 partials per row)
    {
      int row = tid >> 2, seg = tid & 3;
      float mx = -1e30f;
      for (int c = seg * 16; c < seg * 16 + 16; ++c) mx = fmaxf(mx, Ss[row][c]);
      red[row][seg] = mx;
    }
    __syncthreads();
    if (tid < 64) {
      float mx = fmaxf(fmaxf(red[tid][0], red[tid][1]), fmaxf(red[tid][2], red[tid][3]));
      float newm = fmaxf(m_s[tid], mx);
      coef_s[tid] = __expf(m_s[tid] - newm);
      m_s[tid] = newm;
    }
    __syncthreads();
    // P = exp(S - m), row sums
    {
      int row = tid >> 2, seg = tid & 3;
      float sm = 0.f, mrow = m_s[row];
      for (int c = seg * 16; c < seg * 16 + 16; ++c) {
        float p = __expf(Ss[row][c] - mrow);
        Ss[row][c] = p;
        sm += p;
      }
      red[row][seg] = sm;
    }
    __syncthreads();
    if (tid < 64)
      l_s[tid] = l_s[tid] * coef_s[tid] + red[tid][0] + red[tid][1] + red[tid][2] + red[tid][3];
    // rescale running accumulator
#pragma unroll
    for (int i = 0; i < 4; ++i) {
      float cf = coef_s[tr * 4 + i];
#pragma unroll
      for (int j = 0; j < 4; ++j) acc[i][j] *= cf;
    }
    // O += P @ V
    for (int kk = 0; kk < 64; ++kk) {
      float p[4], vv[4];
#pragma unroll
      for (int i = 0; i < 4; ++i) p[i] = Ss[tr * 4 + i][kk];
#pragma unroll
      for (int j = 0; j < 4; ++j) vv[j] = Vs[kk][tc * 4 + j];
#pragma unroll
      for (int i = 0; i < 4; ++i)
#pragma unroll
        for (int j = 0; j < 4; ++j)
          acc[i][j] = fmaf(p[i], vv[j], acc[i][j]);
    }
    __syncthreads();
  }
#pragma unroll
  for (int i = 0; i < 4; ++i) {
    float inv = 1.f / l_s[tr * 4 + i];
#pragma unroll
    for (int j = 0; j < 4; ++j)
      Og[headoff + (size_t)(q0 + tr * 4 + i) * HD + tc * 4 + j] = acc[i][j] * inv;
  }
}

// ---------------------------------------------------------------------------
// GEMM2: out[4096][1024] = silu(O_gathered)[4096][1024] @ w_out[1024][1024]^T + b
// A loader gathers from O in (B,NH,L,HD) layout: feature j -> (nh=j>>6, d=j&63)
// ---------------------------------------------------------------------------
__device__ __forceinline__ float silu_f(float x) { return x / (1.f + __expf(-x)); }

__global__ __launch_bounds__(256) void gemm_out_k(
    const float* __restrict__ O, const float* __restrict__ W,
    const float* __restrict__ bias, float* __restrict__ C) {
  const int K = 1024, N = 1024;
  __shared__ float As[64][17];
  __shared__ float Ws[64][17];
  int tid = threadIdx.x;
  int tr = tid >> 4, tc = tid & 15;
  int m0 = blockIdx.y * 64, n0 = blockIdx.x * 64;
  int lrow = tid >> 2, lkq = (tid & 3) * 4;
  int m = m0 + lrow;
  int bb = m >> 11, l = m & (L_SEQ - 1);
  float acc[4][4] = {};
  for (int k0 = 0; k0 < K; k0 += 16) {
    int k = k0 + lkq;
    int nh = k >> 6, d = k & 63;
    float4 av = *(const float4*)&O[((size_t)(bb * NH + nh) * L_SEQ + l) * HD + d];
    float4 wv = *(const float4*)&W[(size_t)(n0 + lrow) * K + k0 + lkq];
    As[lrow][lkq] = silu_f(av.x); As[lrow][lkq + 1] = silu_f(av.y);
    As[lrow][lkq + 2] = silu_f(av.z); As[lrow][lkq + 3] = silu_f(av.w);
    Ws[lrow][lkq] = wv.x; Ws[lrow][lkq + 1] = wv.y; Ws[lrow][lkq + 2] = wv.z; Ws[lrow][lkq + 3] = wv.w;
    __syncthreads();
#pragma unroll
    for (int kk = 0; kk < 16; ++kk) {
      float a[4], b[4];
#pragma unroll
      for (int i = 0; i < 4; ++i) a[i] = As[tr * 4 + i][kk];
#pragma unroll
      for (int j = 0; j < 4; ++j) b[j] = Ws[tc * 4 + j][kk];
#pragma unroll
      for (int i = 0; i < 4; ++i)
#pragma unroll
        for (int j = 0; j < 4; ++j)
          acc[i][j] = fmaf(a[i], b[j], acc[i][j]);
    }
    __syncthreads();
  }
#pragma unroll
  for (int i = 0; i < 4; ++i)
#pragma unroll
    for (int j = 0; j < 4; ++j)
      C[(size_t)(m0 + tr * 4 + i) * N + n0 + tc * 4 + j] = acc[i][j] + bias[n0 + tc * 4 + j];
}

// ---------------------------------------------------------------------------
extern "C" void kernel_launch(void* const* d_in, const int* in_sizes, int n_in,
                              void* d_out, int out_size, void* d_ws, size_t ws_size,
                              hipStream_t stream) {
  const float* x = (const float*)d_in[0];      // (2, 2048, 1024)
  const float* w_qkv = (const float*)d_in[1];  // (3072, 1024)
  const float* b_qkv = (const float*)d_in[2];  // (3072,)
  const float* w_out = (const float*)d_in[3];  // (1024, 1024)
  const float* b_out = (const float*)d_in[4];  // (1024,)
  float* out = (float*)d_out;                  // (2, 2048, 1024) fp32

  float* ws = (float*)d_ws;
  float* cosb = ws;                      // 65536
  float* sinb = cosb + 65536;            // 65536
  float* qkv = sinb + 65536;             // 4096*3072 = 12,582,912
  float* Q = qkv + 12582912;             // 4,194,304 each
  float* Kb = Q + 4194304;
  float* V = Kb + 4194304;
  float* O = qkv;  // reuse qkv region for attention output (qkv dead by then)

  rope_table_k<<<(L_SEQ * 32 + 255) / 256, 256, 0, stream>>>(cosb, sinb);

  dim3 g1(3072 / 64, 4096 / 64);
  gemm_qkv_k<<<g1, 256, 0, stream>>>(x, w_qkv, b_qkv, qkv);

  int nscatter = B_SZ * L_SEQ * NH * 32;
  rope_scatter_k<<<nscatter / 256, 256, 0, stream>>>(qkv, cosb, sinb, Q, Kb, V);

  attn_k<<<B_SZ * NH * (L_SEQ / 64), 256, 0, stream>>>(Q, Kb, V, O);

  dim3 g2(1024 / 64, 4096 / 64);
  gemm_out_k<<<g2, 256, 0, stream>>>(O, w_out, b_out, out);
}

// Round 2
// 196.086 us; speedup vs baseline: 7.2840x; 7.2840x over previous
//
#include <hip/hip_runtime.h>
#include <math.h>

#define B_SZ 2
#define L_SEQ 2048
#define H_SZ 1024
#define NH 16
#define HD 64

typedef __attribute__((ext_vector_type(8))) short frag_ab;      // 8 bf16 = 4 VGPR
typedef __attribute__((ext_vector_type(4))) float frag_cd;      // 4 f32 acc
typedef __attribute__((ext_vector_type(8))) unsigned short u16x8;
typedef __attribute__((ext_vector_type(4))) unsigned short u16x4;

__device__ __forceinline__ unsigned short f2bf(float f) {
  unsigned int x = __builtin_bit_cast(unsigned int, f);
  x += 0x7fffu + ((x >> 16) & 1u);          // RNE
  return (unsigned short)(x >> 16);
}

// ---------------------------------------------------------------------------
// RoPE tables: combined spatial(16x16 grid, s=l%256) + temporal(ti=l/256)
// rotation angles; two sequential rotations on same pair = angle sum.
// ---------------------------------------------------------------------------
__global__ void rope_table_k(float* __restrict__ cosb, float* __restrict__ sinb) {
  int idx = blockIdx.x * blockDim.x + threadIdx.x;
  if (idx >= L_SEQ * 32) return;
  int l = idx >> 5, j = idx & 31;
  int ti = l >> 8;
  int s = l & 255;
  float ang_s;
  if (j < 16) ang_s = (float)(s & 15) * powf(10000.f, -(float)j / 16.f);
  else        ang_s = (float)(s >> 4) * powf(10000.f, -(float)(j - 16) / 16.f);
  float ang_t = (float)ti * powf(10000.f, -(float)j / 32.f);
  float a = ang_s + ang_t;
  cosb[idx] = cosf(a);
  sinb[idx] = sinf(a);
}

// ---------------------------------------------------------------------------
// fp32 -> bf16 bulk convert (n multiple of 8)
// ---------------------------------------------------------------------------
__global__ void cvt_bf16_k(const float* __restrict__ in, unsigned short* __restrict__ out, int n) {
  int i = (blockIdx.x * blockDim.x + threadIdx.x) * 8;
  if (i >= n) return;
  float4 a = *(const float4*)&in[i];
  float4 b = *(const float4*)&in[i + 4];
  u16x8 o = {f2bf(a.x), f2bf(a.y), f2bf(a.z), f2bf(a.w),
             f2bf(b.x), f2bf(b.y), f2bf(b.z), f2bf(b.w)};
  *(u16x8*)&out[i] = o;
}

// ---------------------------------------------------------------------------
// Generic bf16 MFMA GEMM:  C[M][N] = A[M][K] @ W[N][K]^T + bias   (fp32 out)
// 128x128 tile, BK=32, 4 waves (2x2), 16 mfma_16x16x32 per K-step per wave.
// LDS tiles XOR-swizzled: elem_idx ^ ((row&7)<<3).
// ---------------------------------------------------------------------------
__global__ __launch_bounds__(256) void gemm_mfma_k(
    const unsigned short* __restrict__ A, const unsigned short* __restrict__ W,
    const float* __restrict__ bias, float* __restrict__ C, int M, int N, int K) {
  __shared__ unsigned short As[128 * 32];
  __shared__ unsigned short Ws[128 * 32];
  const frag_cd fzero = {0.f, 0.f, 0.f, 0.f};
  int tid = threadIdx.x;
  int m0 = blockIdx.y * 128, n0 = blockIdx.x * 128;
  int w = tid >> 6, lane = tid & 63, t = lane & 15, g = lane >> 4;
  int wm = w >> 1, wn = w & 1;
  frag_cd acc[4][4];
#pragma unroll
  for (int mi = 0; mi < 4; ++mi)
#pragma unroll
    for (int ni = 0; ni < 4; ++ni) acc[mi][ni] = fzero;

  for (int k0 = 0; k0 < K; k0 += 32) {
#pragma unroll
    for (int it = 0; it < 2; ++it) {
      int c = tid + it * 256;            // 512 chunks of 8 elems per tile
      int row = c >> 2, e0 = (c & 3) * 8;
      u16x8 av = *(const u16x8*)(A + (size_t)(m0 + row) * K + k0 + e0);
      *(u16x8*)&As[(row * 32 + e0) ^ ((row & 7) << 3)] = av;
      u16x8 wv = *(const u16x8*)(W + (size_t)(n0 + row) * K + k0 + e0);
      *(u16x8*)&Ws[(row * 32 + e0) ^ ((row & 7) << 3)] = wv;
    }
    __syncthreads();
    frag_ab af[4], wf[4];
#pragma unroll
    for (int mi = 0; mi < 4; ++mi)
      af[mi] = *(const frag_ab*)&As[(((wm * 64 + mi * 16 + t) * 32) + 8 * g) ^ ((t & 7) << 3)];
#pragma unroll
    for (int ni = 0; ni < 4; ++ni)
      wf[ni] = *(const frag_ab*)&Ws[(((wn * 64 + ni * 16 + t) * 32) + 8 * g) ^ ((t & 7) << 3)];
#pragma unroll
    for (int mi = 0; mi < 4; ++mi)
#pragma unroll
      for (int ni = 0; ni < 4; ++ni)
        acc[mi][ni] = __builtin_amdgcn_mfma_f32_16x16x32_bf16(af[mi], wf[ni], acc[mi][ni], 0, 0, 0);
    __syncthreads();
  }
  // epilogue: D row = g*4+r, col = t (m89/m91-verified layout)
#pragma unroll
  for (int mi = 0; mi < 4; ++mi)
#pragma unroll
    for (int ni = 0; ni < 4; ++ni) {
      int col = n0 + wn * 64 + ni * 16 + t;
      float bv = bias[col];
#pragma unroll
      for (int r = 0; r < 4; ++r)
        C[(size_t)(m0 + wm * 64 + mi * 16 + g * 4 + r) * N + col] = acc[mi][ni][r] + bv;
    }
}

// ---------------------------------------------------------------------------
// RoPE + pack q,k to bf16:  qkv fp32 [(b,l)][3072] -> Qb,Kb [b][n][l][d] bf16
// ---------------------------------------------------------------------------
__global__ void rope_qk_k(const float* __restrict__ qkv,
                          const float* __restrict__ cosb, const float* __restrict__ sinb,
                          unsigned short* __restrict__ Qb, unsigned short* __restrict__ Kb) {
  int tid = blockIdx.x * blockDim.x + threadIdx.x;   // 2*2048*16*32
  int j = tid & 31;
  int n = (tid >> 5) & 15;
  int l = (tid >> 9) & 2047;
  int b = tid >> 20;
  size_t base = ((size_t)(b * L_SEQ + l)) * 3072 + n * 192;
  float cr = cosb[l * 32 + j], sr = sinb[l * 32 + j];
  size_t ob = ((size_t)((b * NH + n) * L_SEQ + l)) * HD + 2 * j;
  float2 q = *(const float2*)&qkv[base + 2 * j];
  float2 k = *(const float2*)&qkv[base + 64 + 2 * j];
  unsigned int qo = (unsigned)f2bf(q.x * cr - q.y * sr) | ((unsigned)f2bf(q.x * sr + q.y * cr) << 16);
  unsigned int ko = (unsigned)f2bf(k.x * cr - k.y * sr) | ((unsigned)f2bf(k.x * sr + k.y * cr) << 16);
  *(unsigned int*)&Qb[ob] = qo;
  *(unsigned int*)&Kb[ob] = ko;
}

// ---------------------------------------------------------------------------
// V transpose to bf16: qkv -> Vt [b][n][d][l]
// ---------------------------------------------------------------------------
__global__ void scatter_v_k(const float* __restrict__ qkv, unsigned short* __restrict__ Vt) {
  int tid = blockIdx.x * blockDim.x + threadIdx.x;   // 2*16*512*64
  int d = tid & 63;
  int rest = tid >> 6;
  int l4 = rest & 511;
  int bn = rest >> 9;          // b*NH+n
  int b = bn >> 4, n = bn & 15;
  int l0 = l4 * 4;
  const float* src = qkv + ((size_t)(b * L_SEQ + l0)) * 3072 + n * 192 + 128 + d;
  u16x4 o;
#pragma unroll
  for (int e = 0; e < 4; ++e) o[e] = f2bf(src[(size_t)e * 3072]);
  *(u16x4*)(Vt + ((size_t)bn * HD + d) * L_SEQ + l0) = o;
}

// ---------------------------------------------------------------------------
// MFMA flash attention (causal). Block = (b,n,qt), 4 waves x 16 q-rows.
// S^T = mfma(K,Q) -> lane owns q-row -> in-reg softmax (shfl_xor 16/32).
// P^T staged per-wave in swizzled LDS; O^T = mfma(V^T, P^T).
// Epilogue: silu + bf16 pack into Og [b][l][h].
// ---------------------------------------------------------------------------
__global__ __launch_bounds__(256) void attn_mfma_k(
    const unsigned short* __restrict__ Qg, const unsigned short* __restrict__ Kg,
    const unsigned short* __restrict__ Vt, unsigned short* __restrict__ Og) {
  __shared__ unsigned short Ks[64 * 64];
  __shared__ unsigned short Vs[64 * 64];
  __shared__ unsigned short Ps[4][16 * 64];
  const frag_cd fzero = {0.f, 0.f, 0.f, 0.f};
  int bx = blockIdx.x;
  int qt = bx & 31;
  int n = (bx >> 5) & 15;
  int b = bx >> 9;
  int q0 = qt * 64;
  int tid = threadIdx.x;
  int w = tid >> 6, lane = tid & 63, t = lane & 15, g = lane >> 4;
  size_t kvbase = ((size_t)(b * NH + n)) * L_SEQ * HD;
  int qrow = q0 + w * 16 + t;

  // Q fragments (B-operand): lane holds Q[qrow][d], d = 32c + 8g .. +8
  const unsigned short* qp = Qg + kvbase + (size_t)qrow * HD;
  frag_ab qf[2];
  qf[0] = *(const frag_ab*)(qp + 8 * g);
  qf[1] = *(const frag_ab*)(qp + 32 + 8 * g);

  frag_cd oacc[4];
#pragma unroll
  for (int db = 0; db < 4; ++db) oacc[db] = fzero;
  float m_run = -1e30f, l_run = 0.f;

  for (int kt = 0; kt <= qt; ++kt) {
    // stage K (rows=key, cols=d) and V^T (rows=d, cols=key), both swizzled
#pragma unroll
    for (int it = 0; it < 2; ++it) {
      int c = tid + it * 256;           // 512 chunks of 8 elems per tile
      int row = c >> 3, e0 = (c & 7) * 8;
      u16x8 kv = *(const u16x8*)(Kg + kvbase + (size_t)(kt * 64 + row) * HD + e0);
      *(u16x8*)&Ks[(row * 64 + e0) ^ ((row & 7) << 3)] = kv;
      u16x8 vv = *(const u16x8*)(Vt + kvbase + (size_t)row * L_SEQ + kt * 64 + e0);
      *(u16x8*)&Vs[(row * 64 + e0) ^ ((row & 7) << 3)] = vv;
    }
    __syncthreads();

    // S^T[k][q]: 4 kb-tiles x 2 d-chunks
    frag_cd st[4];
#pragma unroll
    for (int kb = 0; kb < 4; ++kb) {
      frag_ab k0f = *(const frag_ab*)&Ks[(((kb * 16 + t) * 64) + 8 * g) ^ ((t & 7) << 3)];
      frag_ab k1f = *(const frag_ab*)&Ks[(((kb * 16 + t) * 64) + 32 + 8 * g) ^ ((t & 7) << 3)];
      st[kb] = __builtin_amdgcn_mfma_f32_16x16x32_bf16(k0f, qf[0], fzero, 0, 0, 0);
      st[kb] = __builtin_amdgcn_mfma_f32_16x16x32_bf16(k1f, qf[1], st[kb], 0, 0, 0);
    }

    // online softmax: lane owns q=qrow, k = kt*64 + kb*16 + g*4 + r
    bool diag = (kt == qt);
    float sv[16];
    float mx = -1e30f;
#pragma unroll
    for (int kb = 0; kb < 4; ++kb)
#pragma unroll
      for (int r = 0; r < 4; ++r) {
        float x = st[kb][r] * 0.125f;
        if (diag && (kt * 64 + kb * 16 + g * 4 + r) > qrow) x = -1e30f;
        sv[kb * 4 + r] = x;
        mx = fmaxf(mx, x);
      }
    mx = fmaxf(mx, __shfl_xor(mx, 16));
    mx = fmaxf(mx, __shfl_xor(mx, 32));
    float mnew = fmaxf(m_run, mx);
    float coef = __expf(m_run - mnew);
    float psum = 0.f;
    unsigned short pb[16];
#pragma unroll
    for (int i = 0; i < 16; ++i) {
      float p = __expf(sv[i] - mnew);
      psum += p;
      pb[i] = f2bf(p);
    }
    psum += __shfl_xor(psum, 16);
    psum += __shfl_xor(psum, 32);
    l_run = l_run * coef + psum;
    m_run = mnew;
#pragma unroll
    for (int db = 0; db < 4; ++db) oacc[db] *= coef;

    // write P^T to per-wave LDS [q=t][k], swizzled; then read PV B-frags
    unsigned short* pw = &Ps[w][0];
#pragma unroll
    for (int kb = 0; kb < 4; ++kb) {
      u16x4 pk = {pb[kb * 4], pb[kb * 4 + 1], pb[kb * 4 + 2], pb[kb * 4 + 3]};
      *(u16x4*)&pw[(t * 64 + kb * 16 + g * 4) ^ ((t & 7) << 3)] = pk;
    }
    frag_ab pf[2];
    pf[0] = *(const frag_ab*)&pw[(t * 64 + 8 * g) ^ ((t & 7) << 3)];
    pf[1] = *(const frag_ab*)&pw[(t * 64 + 32 + 8 * g) ^ ((t & 7) << 3)];

    // O^T[d][q] += V^T P^T
#pragma unroll
    for (int db = 0; db < 4; ++db) {
      frag_ab v0f = *(const frag_ab*)&Vs[(((db * 16 + t) * 64) + 8 * g) ^ ((t & 7) << 3)];
      frag_ab v1f = *(const frag_ab*)&Vs[(((db * 16 + t) * 64) + 32 + 8 * g) ^ ((t & 7) << 3)];
      oacc[db] = __builtin_amdgcn_mfma_f32_16x16x32_bf16(v0f, pf[0], oacc[db], 0, 0, 0);
      oacc[db] = __builtin_amdgcn_mfma_f32_16x16x32_bf16(v1f, pf[1], oacc[db], 0, 0, 0);
    }
    __syncthreads();
  }

  // epilogue: o = silu(O/l), lane writes d = db*16 + g*4 + r at row qrow
  float inv = 1.f / l_run;
  size_t obase = ((size_t)b * L_SEQ + qrow) * H_SZ + n * 64;
#pragma unroll
  for (int db = 0; db < 4; ++db) {
    u16x4 ov;
#pragma unroll
    for (int r = 0; r < 4; ++r) {
      float o = oacc[db][r] * inv;
      o = o / (1.f + __expf(-o));
      ov[r] = f2bf(o);
    }
    *(u16x4*)&Og[obase + db * 16 + g * 4] = ov;
  }
}

// ---------------------------------------------------------------------------
extern "C" void kernel_launch(void* const* d_in, const int* in_sizes, int n_in,
                              void* d_out, int out_size, void* d_ws, size_t ws_size,
                              hipStream_t stream) {
  const float* x = (const float*)d_in[0];
  const float* w_qkv = (const float*)d_in[1];
  const float* b_qkv = (const float*)d_in[2];
  const float* w_out = (const float*)d_in[3];
  const float* b_out = (const float*)d_in[4];
  float* out = (float*)d_out;

  float* ws = (float*)d_ws;
  float* cosb = ws;                       // 65536 f32
  float* sinb = cosb + 65536;             // 65536 f32
  float* qkv = sinb + 65536;              // 12,582,912 f32
  unsigned short* us = (unsigned short*)(qkv + 12582912);
  unsigned short* Qb = us;                // 4,194,304 bf16 each
  unsigned short* Kb = Qb + 4194304;
  unsigned short* Vt = Kb + 4194304;
  unsigned short* Og = Vt + 4194304;
  unsigned short* xb = Og + 4194304;      // 4,194,304
  unsigned short* wqkvb = xb + 4194304;   // 3,145,728
  unsigned short* woutb = wqkvb + 3145728; // 1,048,576

  rope_table_k<<<256, 256, 0, stream>>>(cosb, sinb);
  cvt_bf16_k<<<2048, 256, 0, stream>>>(x, xb, 4194304);
  cvt_bf16_k<<<1536, 256, 0, stream>>>(w_qkv, wqkvb, 3145728);
  cvt_bf16_k<<<512, 256, 0, stream>>>(w_out, woutb, 1048576);

  dim3 g1(3072 / 128, 4096 / 128);
  gemm_mfma_k<<<g1, 256, 0, stream>>>(xb, wqkvb, b_qkv, qkv, 4096, 3072, 1024);

  rope_qk_k<<<8192, 256, 0, stream>>>(qkv, cosb, sinb, Qb, Kb);
  scatter_v_k<<<4096, 256, 0, stream>>>(qkv, Vt);

  attn_mfma_k<<<B_SZ * NH * 32, 256, 0, stream>>>(Qb, Kb, Vt, Og);

  dim3 g2(1024 / 128, 4096 / 128);
  gemm_mfma_k<<<g2, 256, 0, stream>>>(Og, woutb, b_out, out, 4096, 1024, 1024);
}

// Round 3
// 138.636 us; speedup vs baseline: 10.3025x; 1.4144x over previous
//
#include <hip/hip_runtime.h>
#include <math.h>

#define B_SZ 2
#define L_SEQ 2048
#define H_SZ 1024
#define NH 16
#define HD 64
#define QSCALE 0.18033688011112042f   // 0.125 * log2(e): S in log2 domain

typedef __attribute__((ext_vector_type(8))) short frag_ab;      // 8 bf16 = 4 VGPR
typedef __attribute__((ext_vector_type(4))) float frag_cd;      // 4 f32 acc
typedef __attribute__((ext_vector_type(8))) unsigned short u16x8;
typedef __attribute__((ext_vector_type(4))) unsigned short u16x4;

__device__ __forceinline__ unsigned short f2bf(float f) {
  unsigned int x = __builtin_bit_cast(unsigned int, f);
  x += 0x7fffu + ((x >> 16) & 1u);          // RNE
  return (unsigned short)(x >> 16);
}

// ---------------------------------------------------------------------------
// RoPE tables: combined spatial(16x16 grid, s=l%256) + temporal(ti=l/256).
// ---------------------------------------------------------------------------
__global__ void rope_table_k(float* __restrict__ cosb, float* __restrict__ sinb) {
  int idx = blockIdx.x * blockDim.x + threadIdx.x;
  if (idx >= L_SEQ * 32) return;
  int l = idx >> 5, j = idx & 31;
  int ti = l >> 8;
  int s = l & 255;
  float ang_s;
  if (j < 16) ang_s = (float)(s & 15) * powf(10000.f, -(float)j / 16.f);
  else        ang_s = (float)(s >> 4) * powf(10000.f, -(float)(j - 16) / 16.f);
  float ang_t = (float)ti * powf(10000.f, -(float)j / 32.f);
  float a = ang_s + ang_t;
  cosb[idx] = cosf(a);
  sinb[idx] = sinf(a);
}

// ---------------------------------------------------------------------------
// fp32 -> bf16 bulk convert (n multiple of 8)
// ---------------------------------------------------------------------------
__global__ void cvt_bf16_k(const float* __restrict__ in, unsigned short* __restrict__ out, int n) {
  int i = (blockIdx.x * blockDim.x + threadIdx.x) * 8;
  if (i >= n) return;
  float4 a = *(const float4*)&in[i];
  float4 b = *(const float4*)&in[i + 4];
  u16x8 o = {f2bf(a.x), f2bf(a.y), f2bf(a.z), f2bf(a.w),
             f2bf(b.x), f2bf(b.y), f2bf(b.z), f2bf(b.w)};
  *(u16x8*)&out[i] = o;
}

// ---------------------------------------------------------------------------
// Generic bf16 MFMA GEMM:  C[M][N] = A[M][K] @ W[N][K]^T + bias   (fp32 out)
// 128x128 tile, BK=32, 4 waves (2x2), issue-early reg staging.
// ---------------------------------------------------------------------------
__global__ __launch_bounds__(256) void gemm_mfma_k(
    const unsigned short* __restrict__ A, const unsigned short* __restrict__ W,
    const float* __restrict__ bias, float* __restrict__ C, int M, int N, int K) {
  __shared__ unsigned short As[128 * 32];
  __shared__ unsigned short Ws[128 * 32];
  const frag_cd fzero = {0.f, 0.f, 0.f, 0.f};
  int tid = threadIdx.x;
  int m0 = blockIdx.y * 128, n0 = blockIdx.x * 128;
  int w = tid >> 6, lane = tid & 63, t = lane & 15, g = lane >> 4;
  int wm = w >> 1, wn = w & 1;
  frag_cd acc[4][4];
#pragma unroll
  for (int mi = 0; mi < 4; ++mi)
#pragma unroll
    for (int ni = 0; ni < 4; ++ni) acc[mi][ni] = fzero;

  int srow = tid >> 2, se0 = (tid & 3) * 8;      // chunk 0 coords (chunk1 = +64 rows)
  u16x8 aV[2], wV[2];
#pragma unroll
  for (int it = 0; it < 2; ++it) {
    aV[it] = *(const u16x8*)(A + (size_t)(m0 + srow + it * 64) * K + se0);
    wV[it] = *(const u16x8*)(W + (size_t)(n0 + srow + it * 64) * K + se0);
  }
  for (int k0 = 0; k0 < K; k0 += 32) {
    if (k0) __syncthreads();
#pragma unroll
    for (int it = 0; it < 2; ++it) {
      int row = srow + it * 64;
      *(u16x8*)&As[(row * 32 + se0) ^ ((row & 7) << 3)] = aV[it];
      *(u16x8*)&Ws[(row * 32 + se0) ^ ((row & 7) << 3)] = wV[it];
    }
    __syncthreads();
    if (k0 + 32 < K) {
#pragma unroll
      for (int it = 0; it < 2; ++it) {
        aV[it] = *(const u16x8*)(A + (size_t)(m0 + srow + it * 64) * K + k0 + 32 + se0);
        wV[it] = *(const u16x8*)(W + (size_t)(n0 + srow + it * 64) * K + k0 + 32 + se0);
      }
    }
    frag_ab af[4], wf[4];
#pragma unroll
    for (int mi = 0; mi < 4; ++mi)
      af[mi] = *(const frag_ab*)&As[(((wm * 64 + mi * 16 + t) * 32) + 8 * g) ^ ((t & 7) << 3)];
#pragma unroll
    for (int ni = 0; ni < 4; ++ni)
      wf[ni] = *(const frag_ab*)&Ws[(((wn * 64 + ni * 16 + t) * 32) + 8 * g) ^ ((t & 7) << 3)];
#pragma unroll
    for (int mi = 0; mi < 4; ++mi)
#pragma unroll
      for (int ni = 0; ni < 4; ++ni)
        acc[mi][ni] = __builtin_amdgcn_mfma_f32_16x16x32_bf16(af[mi], wf[ni], acc[mi][ni], 0, 0, 0);
  }
#pragma unroll
  for (int mi = 0; mi < 4; ++mi)
#pragma unroll
    for (int ni = 0; ni < 4; ++ni) {
      int col = n0 + wn * 64 + ni * 16 + t;
      float bv = bias[col];
#pragma unroll
      for (int r = 0; r < 4; ++r)
        C[(size_t)(m0 + wm * 64 + mi * 16 + g * 4 + r) * N + col] = acc[mi][ni][r] + bv;
    }
}

// ---------------------------------------------------------------------------
// RoPE + pack q,k to bf16 (q pre-scaled by 0.125*log2e for exp2-domain softmax)
// ---------------------------------------------------------------------------
__global__ void rope_qk_k(const float* __restrict__ qkv,
                          const float* __restrict__ cosb, const float* __restrict__ sinb,
                          unsigned short* __restrict__ Qb, unsigned short* __restrict__ Kb) {
  int tid = blockIdx.x * blockDim.x + threadIdx.x;   // 2*2048*16*32
  int j = tid & 31;
  int n = (tid >> 5) & 15;
  int l = (tid >> 9) & 2047;
  int b = tid >> 20;
  size_t base = ((size_t)(b * L_SEQ + l)) * 3072 + n * 192;
  float cr = cosb[l * 32 + j], sr = sinb[l * 32 + j];
  size_t ob = ((size_t)((b * NH + n) * L_SEQ + l)) * HD + 2 * j;
  float2 q = *(const float2*)&qkv[base + 2 * j];
  float2 k = *(const float2*)&qkv[base + 64 + 2 * j];
  unsigned int qo = (unsigned)f2bf((q.x * cr - q.y * sr) * QSCALE) |
                    ((unsigned)f2bf((q.x * sr + q.y * cr) * QSCALE) << 16);
  unsigned int ko = (unsigned)f2bf(k.x * cr - k.y * sr) | ((unsigned)f2bf(k.x * sr + k.y * cr) << 16);
  *(unsigned int*)&Qb[ob] = qo;
  *(unsigned int*)&Kb[ob] = ko;
}

// ---------------------------------------------------------------------------
// V transpose to bf16 via LDS: qkv -> Vt [b][n][d][l]. Block = (b,n,64-l tile).
// ---------------------------------------------------------------------------
__global__ __launch_bounds__(256) void scatter_v_k(const float* __restrict__ qkv,
                                                   unsigned short* __restrict__ Vt) {
  __shared__ unsigned short Ts[64][72];
  int bx = blockIdx.x;
  int lt = bx & 31, n = (bx >> 5) & 15, b = bx >> 9;
  int tid = threadIdx.x;
  int r = tid >> 2, c0 = (tid & 3) * 16;
  const float* src = qkv + (size_t)(b * L_SEQ + lt * 64 + r) * 3072 + n * 192 + 128 + c0;
#pragma unroll
  for (int e = 0; e < 4; ++e) {
    float4 v = *(const float4*)(src + 4 * e);
    Ts[c0 + 4 * e + 0][r] = f2bf(v.x);
    Ts[c0 + 4 * e + 1][r] = f2bf(v.y);
    Ts[c0 + 4 * e + 2][r] = f2bf(v.z);
    Ts[c0 + 4 * e + 3][r] = f2bf(v.w);
  }
  __syncthreads();
  int d = tid >> 2, l0 = (tid & 3) * 16;
  u16x8 a = *(const u16x8*)&Ts[d][l0];
  u16x8 b2 = *(const u16x8*)&Ts[d][l0 + 8];
  unsigned short* dst = Vt + ((size_t)((b * NH + n) * HD + d)) * L_SEQ + lt * 64 + l0;
  *(u16x8*)dst = a;
  *(u16x8*)(dst + 8) = b2;
}

// ---------------------------------------------------------------------------
// One 64x64 S/P/PV tile step for one wave (16 q-rows).
// ---------------------------------------------------------------------------
__device__ __forceinline__ void attn_tile(
    const unsigned short* __restrict__ Ksb, const unsigned short* __restrict__ Vsb,
    unsigned short* __restrict__ pw,
    const frag_ab* qf, frag_cd* oacc, float& m_run, float& l_run,
    int qrow, bool diag, int kt, int t, int g) {
  const frag_cd fzero = {0.f, 0.f, 0.f, 0.f};
  frag_cd st[4];
#pragma unroll
  for (int kb = 0; kb < 4; ++kb) {
    frag_ab k0f = *(const frag_ab*)&Ksb[(((kb * 16 + t) * 64) + 8 * g) ^ ((t & 7) << 3)];
    frag_ab k1f = *(const frag_ab*)&Ksb[(((kb * 16 + t) * 64) + 32 + 8 * g) ^ ((t & 7) << 3)];
    st[kb] = __builtin_amdgcn_mfma_f32_16x16x32_bf16(k0f, qf[0], fzero, 0, 0, 0);
    st[kb] = __builtin_amdgcn_mfma_f32_16x16x32_bf16(k1f, qf[1], st[kb], 0, 0, 0);
  }
  float sv[16];
  float mx = -1e30f;
#pragma unroll
  for (int kb = 0; kb < 4; ++kb)
#pragma unroll
    for (int r = 0; r < 4; ++r) {
      float x = st[kb][r];
      if (diag && (kt * 64 + kb * 16 + g * 4 + r) > qrow) x = -1e30f;
      sv[kb * 4 + r] = x;
      mx = fmaxf(mx, x);
    }
  mx = fmaxf(mx, __shfl_xor(mx, 16));
  mx = fmaxf(mx, __shfl_xor(mx, 32));
  if (__any(mx > m_run)) {                       // defer-rescale
    float mnew = fmaxf(m_run, mx);
    float coef = __builtin_amdgcn_exp2f(m_run - mnew);
#pragma unroll
    for (int db = 0; db < 4; ++db) oacc[db] *= coef;
    l_run *= coef;
    m_run = mnew;
  }
  float psum = 0.f;
  unsigned short pb[16];
#pragma unroll
  for (int i = 0; i < 16; ++i) {
    float p = __builtin_amdgcn_exp2f(sv[i] - m_run);
    psum += p;
    pb[i] = f2bf(p);
  }
  psum += __shfl_xor(psum, 16);
  psum += __shfl_xor(psum, 32);
  l_run += psum;

#pragma unroll
  for (int kb = 0; kb < 4; ++kb) {
    u16x4 pk = {pb[kb * 4], pb[kb * 4 + 1], pb[kb * 4 + 2], pb[kb * 4 + 3]};
    *(u16x4*)&pw[(t * 64 + kb * 16 + g * 4) ^ ((t & 7) << 3)] = pk;
  }
  frag_ab pf0 = *(const frag_ab*)&pw[(t * 64 + 8 * g) ^ ((t & 7) << 3)];
  frag_ab pf1 = *(const frag_ab*)&pw[(t * 64 + 32 + 8 * g) ^ ((t & 7) << 3)];
#pragma unroll
  for (int db = 0; db < 4; ++db) {
    frag_ab v0f = *(const frag_ab*)&Vsb[(((db * 16 + t) * 64) + 8 * g) ^ ((t & 7) << 3)];
    frag_ab v1f = *(const frag_ab*)&Vsb[(((db * 16 + t) * 64) + 32 + 8 * g) ^ ((t & 7) << 3)];
    oacc[db] = __builtin_amdgcn_mfma_f32_16x16x32_bf16(v0f, pf0, oacc[db], 0, 0, 0);
    oacc[db] = __builtin_amdgcn_mfma_f32_16x16x32_bf16(v1f, pf1, oacc[db], 0, 0, 0);
  }
}

// ---------------------------------------------------------------------------
// MFMA flash attention (causal), balanced pairing: block = (b, n, qtA) handles
// q-tiles qtA and 31-qtA over one shared double-buffered K/V stage.
// Every block does exactly 33 tile-works. Epilogue: silu + bf16 pack.
// ---------------------------------------------------------------------------
__global__ __launch_bounds__(256) void attn_mfma_k(
    const unsigned short* __restrict__ Qg, const unsigned short* __restrict__ Kg,
    const unsigned short* __restrict__ Vt, unsigned short* __restrict__ Og) {
  __shared__ unsigned short Ks[2][64 * 64];
  __shared__ unsigned short Vs[2][64 * 64];
  __shared__ unsigned short Ps[4][16 * 64];
  const frag_cd fzero = {0.f, 0.f, 0.f, 0.f};
  int bx = blockIdx.x;
  int qtA = bx & 15;
  int n = (bx >> 4) & 15;
  int b = bx >> 8;
  int qtB = 31 - qtA;
  int tid = threadIdx.x;
  int w = tid >> 6, lane = tid & 63, t = lane & 15, g = lane >> 4;
  size_t kvbase = ((size_t)(b * NH + n)) * L_SEQ * HD;
  int qrowA = qtA * 64 + w * 16 + t;
  int qrowB = qtB * 64 + w * 16 + t;

  const unsigned short* qpA = Qg + kvbase + (size_t)qrowA * HD;
  const unsigned short* qpB = Qg + kvbase + (size_t)qrowB * HD;
  frag_ab qfA[2] = {*(const frag_ab*)(qpA + 8 * g), *(const frag_ab*)(qpA + 32 + 8 * g)};
  frag_ab qfB[2] = {*(const frag_ab*)(qpB + 8 * g), *(const frag_ab*)(qpB + 32 + 8 * g)};

  frag_cd oaccA[4], oaccB[4];
#pragma unroll
  for (int db = 0; db < 4; ++db) { oaccA[db] = fzero; oaccB[db] = fzero; }
  float mA = -1e30f, lA = 0.f, mB = -1e30f, lB = 0.f;

  int srow = tid >> 3, se0 = (tid & 7) * 8;      // chunk 0; chunk 1 = +32 rows
  u16x8 kreg[2], vreg[2];
#pragma unroll
  for (int it = 0; it < 2; ++it) {
    int row = srow + it * 32;
    kreg[it] = *(const u16x8*)(Kg + kvbase + (size_t)row * HD + se0);
    vreg[it] = *(const u16x8*)(Vt + kvbase + (size_t)row * L_SEQ + se0);
  }
#pragma unroll
  for (int it = 0; it < 2; ++it) {
    int row = srow + it * 32;
    *(u16x8*)&Ks[0][(row * 64 + se0) ^ ((row & 7) << 3)] = kreg[it];
    *(u16x8*)&Vs[0][(row * 64 + se0) ^ ((row & 7) << 3)] = vreg[it];
  }

  for (int kt = 0; kt <= qtB; ++kt) {
    int cur = kt & 1;
    __syncthreads();
    bool last = (kt == qtB);
    if (!last) {
#pragma unroll
      for (int it = 0; it < 2; ++it) {
        int row = srow + it * 32;
        kreg[it] = *(const u16x8*)(Kg + kvbase + (size_t)((kt + 1) * 64 + row) * HD + se0);
        vreg[it] = *(const u16x8*)(Vt + kvbase + (size_t)row * L_SEQ + (kt + 1) * 64 + se0);
      }
    }
    attn_tile(&Ks[cur][0], &Vs[cur][0], &Ps[w][0], qfB, oaccB, mB, lB, qrowB, kt == qtB, kt, t, g);
    if (kt <= qtA)
      attn_tile(&Ks[cur][0], &Vs[cur][0], &Ps[w][0], qfA, oaccA, mA, lA, qrowA, kt == qtA, kt, t, g);
    if (!last) {
      int nxt = cur ^ 1;
#pragma unroll
      for (int it = 0; it < 2; ++it) {
        int row = srow + it * 32;
        *(u16x8*)&Ks[nxt][(row * 64 + se0) ^ ((row & 7) << 3)] = kreg[it];
        *(u16x8*)&Vs[nxt][(row * 64 + se0) ^ ((row & 7) << 3)] = vreg[it];
      }
    }
  }

  // epilogue: o = silu(O/l), lane writes d = db*16 + g*4 + r at row qrow
  size_t ob0 = (size_t)b * L_SEQ * H_SZ + n * 64;
#pragma unroll
  for (int side = 0; side < 2; ++side) {
    frag_cd* oacc = side ? oaccA : oaccB;
    float inv = 1.f / (side ? lA : lB);
    int qrow = side ? qrowA : qrowB;
#pragma unroll
    for (int db = 0; db < 4; ++db) {
      u16x4 ov;
#pragma unroll
      for (int r = 0; r < 4; ++r) {
        float o = oacc[db][r] * inv;
        o = o / (1.f + __expf(-o));
        ov[r] = f2bf(o);
      }
      *(u16x4*)&Og[ob0 + (size_t)qrow * H_SZ + db * 16 + g * 4] = ov;
    }
  }
}

// ---------------------------------------------------------------------------
extern "C" void kernel_launch(void* const* d_in, const int* in_sizes, int n_in,
                              void* d_out, int out_size, void* d_ws, size_t ws_size,
                              hipStream_t stream) {
  const float* x = (const float*)d_in[0];
  const float* w_qkv = (const float*)d_in[1];
  const float* b_qkv = (const float*)d_in[2];
  const float* w_out = (const float*)d_in[3];
  const float* b_out = (const float*)d_in[4];
  float* out = (float*)d_out;

  float* ws = (float*)d_ws;
  float* cosb = ws;                       // 65536 f32
  float* sinb = cosb + 65536;             // 65536 f32
  float* qkv = sinb + 65536;              // 12,582,912 f32
  unsigned short* us = (unsigned short*)(qkv + 12582912);
  unsigned short* Qb = us;                // 4,194,304 bf16 each
  unsigned short* Kb = Qb + 4194304;
  unsigned short* Vt = Kb + 4194304;
  unsigned short* Og = Vt + 4194304;
  unsigned short* xb = Og + 4194304;      // 4,194,304
  unsigned short* wqkvb = xb + 4194304;   // 3,145,728
  unsigned short* woutb = wqkvb + 3145728; // 1,048,576

  rope_table_k<<<256, 256, 0, stream>>>(cosb, sinb);
  cvt_bf16_k<<<2048, 256, 0, stream>>>(x, xb, 4194304);
  cvt_bf16_k<<<1536, 256, 0, stream>>>(w_qkv, wqkvb, 3145728);
  cvt_bf16_k<<<512, 256, 0, stream>>>(w_out, woutb, 1048576);

  dim3 g1(3072 / 128, 4096 / 128);
  gemm_mfma_k<<<g1, 256, 0, stream>>>(xb, wqkvb, b_qkv, qkv, 4096, 3072, 1024);

  rope_qk_k<<<8192, 256, 0, stream>>>(qkv, cosb, sinb, Qb, Kb);
  scatter_v_k<<<1024, 256, 0, stream>>>(qkv, Vt);

  attn_mfma_k<<<B_SZ * NH * 16, 256, 0, stream>>>(Qb, Kb, Vt, Og);

  dim3 g2(1024 / 128, 4096 / 128);
  gemm_mfma_k<<<g2, 256, 0, stream>>>(Og, woutb, b_out, out, 4096, 1024, 1024);
}